// Round 2
// baseline (1398.371 us; speedup 1.0000x reference)
//
#include <hip/hip_runtime.h>
#include <hip/hip_bf16.h>

// ---------------------------------------------------------------------------
// VanillaLSTM forward, persistent-RNN style. FP32 global I/O, bf16 MFMA core.
// B=4096 seqs / 256 blocks -> 16 rows per block, one block per CU.
// 512 threads = 8 waves; wave w owns cell-channel slice j in [w*16, w*16+16).
// W_ih / W_hh fragments (converted fp32->bf16 once) live in VGPRs for the
// whole kernel (weights-stationary). h round-trips through double-buffered
// LDS (bf16); c stays in fp32 registers. One __syncthreads per time step.
// ---------------------------------------------------------------------------

#define B_TOT 4096
#define T_LEN 1024
#define D_INP 2
#define EMD   128
#define CELL  128
#define D_OUT 5

#define ROWS  16               // batch rows per block (MFMA M)
#define WAVES 8
#define BLOCK (WAVES * 64)
#define LDH   136              // padded LDS row stride in shorts

typedef short s8v  __attribute__((ext_vector_type(8)));   // 8 x bf16 (4 VGPRs) MFMA frag
typedef short s4v  __attribute__((ext_vector_type(4)));
typedef float f32x4 __attribute__((ext_vector_type(4)));

#if __has_builtin(__builtin_amdgcn_exp2f)
#define EXP2F(x) __builtin_amdgcn_exp2f(x)
#else
#define EXP2F(x) exp2f(x)
#endif
#if __has_builtin(__builtin_amdgcn_rcpf)
#define RCPF(x) __builtin_amdgcn_rcpf(x)
#else
#define RCPF(x) (1.0f / (x))
#endif

__device__ __forceinline__ float bf2f(short s) {
    unsigned int u = ((unsigned int)(unsigned short)s) << 16;
    return __builtin_bit_cast(float, u);
}
__device__ __forceinline__ short f2bf(float f) {
    unsigned int u = __builtin_bit_cast(unsigned int, f);
    u += 0x7fffu + ((u >> 16) & 1u);          // round to nearest even
    return (short)(u >> 16);
}
__device__ __forceinline__ float sigm(float x) {
    return RCPF(1.0f + EXP2F(-1.44269504f * x));
}
__device__ __forceinline__ float tanh_fast(float x) {
    // tanh(x) = 2*sigmoid(2x) - 1 ; exact at +-inf
    return 2.0f * RCPF(1.0f + EXP2F(-2.88539008f * x)) - 1.0f;
}
// load 8 consecutive fp32, convert to a bf16x8 MFMA fragment
__device__ __forceinline__ s8v load8_f32_to_bf16(const float* p) {
    float4 a = *(const float4*)p;
    float4 b = *(const float4*)(p + 4);
    s8v r;
    r[0] = f2bf(a.x); r[1] = f2bf(a.y); r[2] = f2bf(a.z); r[3] = f2bf(a.w);
    r[4] = f2bf(b.x); r[5] = f2bf(b.y); r[6] = f2bf(b.z); r[7] = f2bf(b.w);
    return r;
}

__global__ __launch_bounds__(BLOCK, 1)
void lstm_persistent(const float* __restrict__ x,     // [B,T,2] fp32
                     const float* __restrict__ We,    // [128,2]
                     const float* __restrict__ be,    // [128]
                     const float* __restrict__ Wih,   // [512,128]
                     const float* __restrict__ Whh,   // [512,128]
                     const float* __restrict__ bih,   // [512]
                     const float* __restrict__ bhh,   // [512]
                     const float* __restrict__ Wo,    // [5,128]
                     const float* __restrict__ bo,    // [5]
                     float* __restrict__ out)         // y[B,T,5] | h[B,128] | c[B,128]
{
    __shared__ short h_lds[2][ROWS][LDH];
    __shared__ short e_lds[2][ROWS][LDH];

    const int tid  = threadIdx.x;
    const int lane = tid & 63;
    const int w    = tid >> 6;         // wave 0..7
    const int n16  = lane & 15;        // frag row/col within 16
    const int q    = lane >> 4;        // quad 0..3
    const int q8   = q * 8;
    const int b0   = blockIdx.x * ROWS;
    const int jcol = w * 16 + n16;     // this lane's cell channel (0..127)

    float* out_y = out;
    float* out_h = out + (size_t)B_TOT * T_LEN * D_OUT;
    float* out_c = out_h + (size_t)B_TOT * CELL;

    // ---- persistent weight fragments (B^T layout: W[n][k], n=lane&15, k=q*8+j) ----
    s8v wih_f[4][4], whh_f[4][4];      // [gate i/f/g/o][ktile]
    #pragma unroll
    for (int g = 0; g < 4; ++g) {
        const int row = g * CELL + jcol;
        #pragma unroll
        for (int kt = 0; kt < 4; ++kt) {
            wih_f[g][kt] = load8_f32_to_bf16(Wih + row * EMD  + kt * 32 + q8);
            whh_f[g][kt] = load8_f32_to_bf16(Whh + row * CELL + kt * 32 + q8);
        }
    }
    float bias_g[4];
    #pragma unroll
    for (int g = 0; g < 4; ++g)
        bias_g[g] = bih[g * CELL + jcol] + bhh[g * CELL + jcol];

    // ---- wave 0: output projection weights (cols >= 5 zeroed, never stored) ----
    s8v wo_f[4];
    float bo_v = 0.0f;
    {
        s8v z = {0, 0, 0, 0, 0, 0, 0, 0};
        #pragma unroll
        for (int kt = 0; kt < 4; ++kt) wo_f[kt] = z;
        if (w == 0 && n16 < D_OUT) {
            #pragma unroll
            for (int kt = 0; kt < 4; ++kt)
                wo_f[kt] = load8_f32_to_bf16(Wo + n16 * CELL + kt * 32 + q8);
            bo_v = bo[n16];
        }
    }

    // ---- embedding constants: thread handles row er, e-cols jj0..jj0+3 ----
    const int er  = tid >> 5;           // 0..15
    const int jj0 = (tid & 31) * 4;     // 0..124
    float weA[4], weB[4], bev[4];
    #pragma unroll
    for (int jl = 0; jl < 4; ++jl) {
        weA[jl] = We[(jj0 + jl) * 2 + 0];
        weB[jl] = We[(jj0 + jl) * 2 + 1];
        bev[jl] = be[jj0 + jl];
    }
    const float* xrow = x + (size_t)(b0 + er) * T_LEN * D_INP;

    // ---- prologue: h_0 = 0, e_0 into buffer 0 ----
    {
        unsigned int* hz = (unsigned int*)&h_lds[0][0][0];
        for (int i = tid; i < ROWS * LDH / 2; i += BLOCK) hz[i] = 0u;

        float2 xd = *(const float2*)(xrow);
        s4v ev;
        #pragma unroll
        for (int jl = 0; jl < 4; ++jl)
            ev[jl] = f2bf(fmaxf(xd.x * weA[jl] + xd.y * weB[jl] + bev[jl], 0.0f));
        *(s4v*)&e_lds[0][er][jj0] = ev;
    }

    float c_r[4] = {0.0f, 0.0f, 0.0f, 0.0f};

    // ======================= time loop =======================
    #pragma unroll 1
    for (int u = 0; u < T_LEN; ++u) {
        const int p = u & 1;
        __syncthreads();   // h_lds[p]=h_u and e_lds[p]=e_u visible; prior reads drained

        // A-fragments (A[m=lane&15][k=q*8+j]) from LDS
        s8v ah[4], ae[4];
        #pragma unroll
        for (int kt = 0; kt < 4; ++kt) {
            ah[kt] = *(const s8v*)&h_lds[p][n16][kt * 32 + q8];
            ae[kt] = *(const s8v*)&e_lds[p][n16][kt * 32 + q8];
        }

        // wave 0: y_{u-1} = h_u @ Wo^T + bo (lagged one step)
        if (w == 0 && u > 0) {
            f32x4 ay = {bo_v, bo_v, bo_v, bo_v};
            #pragma unroll
            for (int kt = 0; kt < 4; ++kt)
                ay = __builtin_amdgcn_mfma_f32_16x16x32_bf16(ah[kt], wo_f[kt], ay, 0, 0, 0);
            if (n16 < D_OUT) {
                #pragma unroll
                for (int r = 0; r < 4; ++r)
                    out_y[((size_t)(b0 + q * 4 + r) * T_LEN + (u - 1)) * D_OUT + n16] = ay[r];
            }
        }

        // gates = e_u @ Wih^T + h_u @ Whh^T + (b_ih + b_hh), fp32 accum
        f32x4 acc[4];
        #pragma unroll
        for (int g = 0; g < 4; ++g) {
            f32x4 a = {bias_g[g], bias_g[g], bias_g[g], bias_g[g]};
            #pragma unroll
            for (int kt = 0; kt < 4; ++kt) {
                a = __builtin_amdgcn_mfma_f32_16x16x32_bf16(ah[kt], whh_f[g][kt], a, 0, 0, 0);
                a = __builtin_amdgcn_mfma_f32_16x16x32_bf16(ae[kt], wih_f[g][kt], a, 0, 0, 0);
            }
            acc[g] = a;
        }

        // elementwise in registers; C/D layout row = q*4+r, col = jcol
        #pragma unroll
        for (int r = 0; r < 4; ++r) {
            float iv = sigm(acc[0][r]);
            float fv = sigm(acc[1][r]);
            float gv = tanh_fast(acc[2][r]);
            float ov = sigm(acc[3][r]);
            c_r[r] = fv * c_r[r] + iv * gv;
            float hv = ov * tanh_fast(c_r[r]);
            h_lds[1 - p][q * 4 + r][jcol] = f2bf(hv);   // h_{u+1}
        }

        // e_{u+1} into the other buffer (x clamped at the last step)
        {
            const int tn = (u + 1 < T_LEN) ? (u + 1) : (T_LEN - 1);
            float2 xd = *(const float2*)(xrow + tn * D_INP);
            s4v ev;
            #pragma unroll
            for (int jl = 0; jl < 4; ++jl)
                ev[jl] = f2bf(fmaxf(xd.x * weA[jl] + xd.y * weB[jl] + bev[jl], 0.0f));
            *(s4v*)&e_lds[1 - p][er][jj0] = ev;
        }
    }

    // ======================= epilogue =======================
    __syncthreads();   // h_T lives in h_lds[0] (written by iter 1023)

    // y_{T-1} = h_T @ Wo^T + bo
    if (w == 0) {
        s8v ah[4];
        #pragma unroll
        for (int kt = 0; kt < 4; ++kt)
            ah[kt] = *(const s8v*)&h_lds[0][n16][kt * 32 + q8];
        f32x4 ay = {bo_v, bo_v, bo_v, bo_v};
        #pragma unroll
        for (int kt = 0; kt < 4; ++kt)
            ay = __builtin_amdgcn_mfma_f32_16x16x32_bf16(ah[kt], wo_f[kt], ay, 0, 0, 0);
        if (n16 < D_OUT) {
            #pragma unroll
            for (int r = 0; r < 4; ++r)
                out_y[((size_t)(b0 + q * 4 + r) * T_LEN + (T_LEN - 1)) * D_OUT + n16] = ay[r];
        }
    }

    // final c (fp32 registers, C/D layout)
    #pragma unroll
    for (int r = 0; r < 4; ++r)
        out_c[(size_t)(b0 + q * 4 + r) * CELL + jcol] = c_r[r];

    // final h (from LDS bf16 -> fp32, coalesced 16B stores)
    {
        const int m  = (tid * 4) >> 7;      // 0..15
        const int k0 = (tid * 4) & 127;
        s4v hv = *(const s4v*)&h_lds[0][m][k0];
        float4 hf;
        hf.x = bf2f(hv[0]); hf.y = bf2f(hv[1]);
        hf.z = bf2f(hv[2]); hf.w = bf2f(hv[3]);
        *(float4*)(out_h + (size_t)(b0 + m) * CELL + k0) = hf;
    }
}

extern "C" void kernel_launch(void* const* d_in, const int* in_sizes, int n_in,
                              void* d_out, int out_size, void* d_ws, size_t ws_size,
                              hipStream_t stream) {
    const float* x   = (const float*)d_in[0];
    const float* We  = (const float*)d_in[1];
    const float* be  = (const float*)d_in[2];
    const float* Wih = (const float*)d_in[3];
    const float* Whh = (const float*)d_in[4];
    const float* bih = (const float*)d_in[5];
    const float* bhh = (const float*)d_in[6];
    const float* Wo  = (const float*)d_in[7];
    const float* bo  = (const float*)d_in[8];
    float* out = (float*)d_out;

    dim3 grid(B_TOT / ROWS);   // 256 blocks, one per CU
    dim3 block(BLOCK);         // 512 threads = 8 waves
    hipLaunchKernelGGL(lstm_persistent, grid, block, 0, stream,
                       x, We, be, Wih, Whh, bih, bhh, Wo, bo, out);
}

// Round 3
// 1393.750 us; speedup vs baseline: 1.0033x; 1.0033x over previous
//
#include <hip/hip_runtime.h>
#include <hip/hip_bf16.h>

// ---------------------------------------------------------------------------
// VanillaLSTM forward, persistent-RNN style. FP32 global I/O, bf16 MFMA core.
// B=4096 seqs / 256 blocks -> 16 rows per block, one block per CU.
// 512 threads = 8 waves; wave w owns cell-channel slice [w*16, w*16+16).
//
// Round 3 changes vs round 2:
//  * MFMA operand-role swap: D[m=channel][n=batch row] (A=weights, B=state).
//    Same weight/state fragments, swapped intrinsic args. Each lane now owns
//    4 CONSECUTIVE channels x 1 row -> h written as one ds_write_b64 (<=2-way
//    bank aliasing = free), c/h stored as float4.
//  * lgkm-only barrier (asm s_waitcnt lgkmcnt(0); s_barrier) -- no vmcnt(0)
//    drain per step; y-stores / x-loads stream freely.
//  * x-load hoisted to top of step (latency hidden behind MFMAs).
//  * bf16 pack via +0x8000 ties-away (1 VALU op per value).
// ---------------------------------------------------------------------------

#define B_TOT 4096
#define T_LEN 1024
#define D_INP 2
#define EMD   128
#define CELL  128
#define D_OUT 5

#define ROWS  16               // batch rows per block (MFMA N now)
#define WAVES 8
#define BLOCK (WAVES * 64)
#define LDH   136              // padded LDS row stride in shorts

typedef short s8v  __attribute__((ext_vector_type(8)));   // 8 x bf16 MFMA frag
typedef short s4v  __attribute__((ext_vector_type(4)));
typedef float f32x4 __attribute__((ext_vector_type(4)));

#define BAR() asm volatile("s_waitcnt lgkmcnt(0)\n\ts_barrier" ::: "memory")

#if __has_builtin(__builtin_amdgcn_exp2f)
#define EXP2F(x) __builtin_amdgcn_exp2f(x)
#else
#define EXP2F(x) exp2f(x)
#endif
#if __has_builtin(__builtin_amdgcn_rcpf)
#define RCPF(x) __builtin_amdgcn_rcpf(x)
#else
#define RCPF(x) (1.0f / (x))
#endif

__device__ __forceinline__ float bf2f(short s) {
    unsigned int u = ((unsigned int)(unsigned short)s) << 16;
    return __builtin_bit_cast(float, u);
}
__device__ __forceinline__ short f2bf(float f) {   // RNE (init-time only)
    unsigned int u = __builtin_bit_cast(unsigned int, f);
    u += 0x7fffu + ((u >> 16) & 1u);
    return (short)(u >> 16);
}
// pack two fp32 -> two bf16 in one dword, round-nearest (ties away): cheap
__device__ __forceinline__ unsigned int pk_bf16(float a, float b) {
    unsigned int ua = __builtin_bit_cast(unsigned int, a);
    unsigned int ub = __builtin_bit_cast(unsigned int, b);
    return ((ua + 0x8000u) >> 16) | ((ub + 0x8000u) & 0xffff0000u);
}
__device__ __forceinline__ float sigm(float x) {
    return RCPF(1.0f + EXP2F(-1.44269504f * x));
}
__device__ __forceinline__ float tanh_fast(float x) {
    return 2.0f * RCPF(1.0f + EXP2F(-2.88539008f * x)) - 1.0f;
}
__device__ __forceinline__ s8v load8_f32_to_bf16(const float* p) {
    float4 a = *(const float4*)p;
    float4 b = *(const float4*)(p + 4);
    s8v r;
    r[0] = f2bf(a.x); r[1] = f2bf(a.y); r[2] = f2bf(a.z); r[3] = f2bf(a.w);
    r[4] = f2bf(b.x); r[5] = f2bf(b.y); r[6] = f2bf(b.z); r[7] = f2bf(b.w);
    return r;
}

__global__ __launch_bounds__(BLOCK, 1)
void lstm_persistent(const float* __restrict__ x,     // [B,T,2]
                     const float* __restrict__ We,    // [128,2]
                     const float* __restrict__ be,    // [128]
                     const float* __restrict__ Wih,   // [512,128]
                     const float* __restrict__ Whh,   // [512,128]
                     const float* __restrict__ bih,   // [512]
                     const float* __restrict__ bhh,   // [512]
                     const float* __restrict__ Wo,    // [5,128]
                     const float* __restrict__ bo,    // [5]
                     float* __restrict__ out)         // y[B,T,5] | h[B,128] | c[B,128]
{
    __shared__ short h_lds[2][ROWS][LDH];   // [row][channel], bf16
    __shared__ short e_lds[2][ROWS][LDH];

    const int tid  = threadIdx.x;
    const int lane = tid & 63;
    const int w    = tid >> 6;         // wave 0..7
    const int n16  = lane & 15;        // B-operand index: batch row
    const int q    = lane >> 4;        // quad 0..3
    const int q8   = q * 8;
    const int b0   = blockIdx.x * ROWS;
    const int ch0  = w * 16 + q * 4;   // first of this lane's 4 channels

    float* out_y = out;
    float* out_h = out + (size_t)B_TOT * T_LEN * D_OUT;
    float* out_c = out_h + (size_t)B_TOT * CELL;

    // ---- persistent weight fragments, A-operand layout A[m][k]:
    //      m = lane&15 -> channel (w*16+n16), k = q*8+j ----
    s8v wih_f[4][4], whh_f[4][4];      // [gate i/f/g/o][ktile]
    #pragma unroll
    for (int g = 0; g < 4; ++g) {
        const int row = g * CELL + w * 16 + n16;
        #pragma unroll
        for (int kt = 0; kt < 4; ++kt) {
            wih_f[g][kt] = load8_f32_to_bf16(Wih + row * EMD  + kt * 32 + q8);
            whh_f[g][kt] = load8_f32_to_bf16(Whh + row * CELL + kt * 32 + q8);
        }
    }
    // per-lane biases for its 4 channels (C/D row = q*4+r -> channel ch0+r)
    float4 bias4[4];
    #pragma unroll
    for (int g = 0; g < 4; ++g) {
        float4 bi = *(const float4*)(bih + g * CELL + ch0);
        float4 bh = *(const float4*)(bhh + g * CELL + ch0);
        bias4[g] = make_float4(bi.x + bh.x, bi.y + bh.y, bi.z + bh.z, bi.w + bh.w);
    }

    // ---- wave 0: output projection. A-operand: m=lane&15 -> out-channel ----
    s8v wo_f[4];
    float bo_r[4];
    {
        s8v z = {0, 0, 0, 0, 0, 0, 0, 0};
        #pragma unroll
        for (int kt = 0; kt < 4; ++kt) wo_f[kt] = z;
        if (w == 0 && n16 < D_OUT) {
            #pragma unroll
            for (int kt = 0; kt < 4; ++kt)
                wo_f[kt] = load8_f32_to_bf16(Wo + n16 * CELL + kt * 32 + q8);
        }
        #pragma unroll
        for (int r = 0; r < 4; ++r) {
            const int oc = q * 4 + r;
            bo_r[r] = (w == 0 && oc < D_OUT) ? bo[oc] : 0.0f;
        }
    }

    // ---- embedding constants: thread handles row er, e-cols jj0..jj0+3 ----
    const int er  = tid >> 5;           // 0..15
    const int jj0 = (tid & 31) * 4;     // 0..124
    float weA[4], weB[4], bev[4];
    #pragma unroll
    for (int jl = 0; jl < 4; ++jl) {
        weA[jl] = We[(jj0 + jl) * 2 + 0];
        weB[jl] = We[(jj0 + jl) * 2 + 1];
        bev[jl] = be[jj0 + jl];
    }
    const float* xrow = x + (size_t)(b0 + er) * T_LEN * D_INP;

    // ---- prologue: h_0 = 0, e_0 into buffer 0 ----
    {
        unsigned int* hz = (unsigned int*)&h_lds[0][0][0];
        for (int i = tid; i < ROWS * LDH / 2; i += BLOCK) hz[i] = 0u;

        float2 xd = *(const float2*)(xrow);
        float e0 = fmaxf(xd.x * weA[0] + xd.y * weB[0] + bev[0], 0.0f);
        float e1 = fmaxf(xd.x * weA[1] + xd.y * weB[1] + bev[1], 0.0f);
        float e2 = fmaxf(xd.x * weA[2] + xd.y * weB[2] + bev[2], 0.0f);
        float e3 = fmaxf(xd.x * weA[3] + xd.y * weB[3] + bev[3], 0.0f);
        unsigned int u01 = pk_bf16(e0, e1), u23 = pk_bf16(e2, e3);
        *(unsigned int*)&e_lds[0][er][jj0]     = u01;
        *(unsigned int*)&e_lds[0][er][jj0 + 2] = u23;
    }

    float c_r[4] = {0.0f, 0.0f, 0.0f, 0.0f};

    // ======================= time loop =======================
    #pragma unroll 1
    for (int u = 0; u < T_LEN; ++u) {
        const int p = u & 1;
        BAR();   // lgkm-only: h_lds[p], e_lds[p] visible; our reads drained

        // prefetch x for step u+1 early (latency hides behind MFMAs)
        const int tn = (u + 1 < T_LEN) ? (u + 1) : (T_LEN - 1);
        float2 xd = *(const float2*)(xrow + tn * D_INP);

        // state fragments, B-operand layout B[n=row=lane&15][k=q*8+j]
        s8v ah[4], ae[4];
        #pragma unroll
        for (int kt = 0; kt < 4; ++kt) {
            ah[kt] = *(const s8v*)&h_lds[p][n16][kt * 32 + q8];
            ae[kt] = *(const s8v*)&e_lds[p][n16][kt * 32 + q8];
        }

        // wave 0: y_{u-1} = Wo @ h_u^T (lagged). D[m=outch][n=row]
        if (w == 0 && u > 0) {
            f32x4 ay = {bo_r[0], bo_r[1], bo_r[2], bo_r[3]};
            #pragma unroll
            for (int kt = 0; kt < 4; ++kt)
                ay = __builtin_amdgcn_mfma_f32_16x16x32_bf16(wo_f[kt], ah[kt], ay, 0, 0, 0);
            float* yp = out_y + ((size_t)(b0 + n16) * T_LEN + (u - 1)) * D_OUT;
            if (q == 0) {
                yp[0] = ay[0]; yp[1] = ay[1]; yp[2] = ay[2]; yp[3] = ay[3];
            } else if (q == 1) {
                yp[4] = ay[0];
            }
        }

        // gates^T = Wih @ e^T + Whh @ h^T + bias. D[m=channel][n=row]
        f32x4 acc[4];
        #pragma unroll
        for (int g = 0; g < 4; ++g) {
            f32x4 a = {bias4[g].x, bias4[g].y, bias4[g].z, bias4[g].w};
            #pragma unroll
            for (int kt = 0; kt < 4; ++kt) {
                a = __builtin_amdgcn_mfma_f32_16x16x32_bf16(whh_f[g][kt], ah[kt], a, 0, 0, 0);
                a = __builtin_amdgcn_mfma_f32_16x16x32_bf16(wih_f[g][kt], ae[kt], a, 0, 0, 0);
            }
            acc[g] = a;
        }

        // elementwise: lane owns channels ch0..ch0+3 of batch row n16
        float hv[4];
        #pragma unroll
        for (int r = 0; r < 4; ++r) {
            float iv = sigm(acc[0][r]);
            float fv = sigm(acc[1][r]);
            float gv = tanh_fast(acc[2][r]);
            float ov = sigm(acc[3][r]);
            c_r[r] = fv * c_r[r] + iv * gv;
            hv[r] = ov * tanh_fast(c_r[r]);
        }
        // h_{u+1}: 4 consecutive bf16 = one 8B LDS write (<=2-way banking)
        {
            unsigned int u01 = pk_bf16(hv[0], hv[1]);
            unsigned int u23 = pk_bf16(hv[2], hv[3]);
            unsigned int* hp = (unsigned int*)&h_lds[1 - p][n16][ch0];
            hp[0] = u01; hp[1] = u23;
        }
        if (u == T_LEN - 1) {   // final h, fp32 from registers (uniform branch)
            *(float4*)(out_h + (size_t)(b0 + n16) * CELL + ch0) =
                make_float4(hv[0], hv[1], hv[2], hv[3]);
        }

        // e_{u+1} into the other buffer
        {
            float e0 = fmaxf(xd.x * weA[0] + xd.y * weB[0] + bev[0], 0.0f);
            float e1 = fmaxf(xd.x * weA[1] + xd.y * weB[1] + bev[1], 0.0f);
            float e2 = fmaxf(xd.x * weA[2] + xd.y * weB[2] + bev[2], 0.0f);
            float e3 = fmaxf(xd.x * weA[3] + xd.y * weB[3] + bev[3], 0.0f);
            unsigned int u01 = pk_bf16(e0, e1), u23 = pk_bf16(e2, e3);
            unsigned int* ep = (unsigned int*)&e_lds[1 - p][er][jj0];
            ep[0] = u01; ep[1] = u23;
        }
    }

    // ======================= epilogue =======================
    BAR();   // h_T lives in h_lds[0] (iter 1023 wrote buffer 0)

    if (w == 0) {   // y_{T-1} = Wo @ h_T^T
        s8v ah[4];
        #pragma unroll
        for (int kt = 0; kt < 4; ++kt)
            ah[kt] = *(const s8v*)&h_lds[0][n16][kt * 32 + q8];
        f32x4 ay = {bo_r[0], bo_r[1], bo_r[2], bo_r[3]};
        #pragma unroll
        for (int kt = 0; kt < 4; ++kt)
            ay = __builtin_amdgcn_mfma_f32_16x16x32_bf16(wo_f[kt], ah[kt], ay, 0, 0, 0);
        float* yp = out_y + ((size_t)(b0 + n16) * T_LEN + (T_LEN - 1)) * D_OUT;
        if (q == 0) {
            yp[0] = ay[0]; yp[1] = ay[1]; yp[2] = ay[2]; yp[3] = ay[3];
        } else if (q == 1) {
            yp[4] = ay[0];
        }
    }

    // final c: 4 consecutive channels -> one float4 store
    *(float4*)(out_c + (size_t)(b0 + n16) * CELL + ch0) =
        make_float4(c_r[0], c_r[1], c_r[2], c_r[3]);
}

extern "C" void kernel_launch(void* const* d_in, const int* in_sizes, int n_in,
                              void* d_out, int out_size, void* d_ws, size_t ws_size,
                              hipStream_t stream) {
    const float* x   = (const float*)d_in[0];
    const float* We  = (const float*)d_in[1];
    const float* be  = (const float*)d_in[2];
    const float* Wih = (const float*)d_in[3];
    const float* Whh = (const float*)d_in[4];
    const float* bih = (const float*)d_in[5];
    const float* bhh = (const float*)d_in[6];
    const float* Wo  = (const float*)d_in[7];
    const float* bo  = (const float*)d_in[8];
    float* out = (float*)d_out;

    dim3 grid(B_TOT / ROWS);   // 256 blocks, one per CU
    dim3 block(BLOCK);         // 512 threads = 8 waves
    hipLaunchKernelGGL(lstm_persistent, grid, block, 0, stream,
                       x, We, be, Wih, Whh, bih, bhh, Wo, bo, out);
}

// Round 5
// 1320.441 us; speedup vs baseline: 1.0590x; 1.0555x over previous
//
#include <hip/hip_runtime.h>
#include <hip/hip_bf16.h>
#include <type_traits>

// ---------------------------------------------------------------------------
// VanillaLSTM forward, persistent-RNN style. FP32 global I/O, bf16 MFMA core.
// B=4096 seqs / 256 blocks -> 16 rows per block, one block per CU.
// 512 threads = 8 waves; wave w owns cell-channel slice [w*16, w*16+16).
// Weights-stationary in VGPRs (caps us at 2 waves/SIMD -- by design).
//
// Round 5 = Round 4 logic, macro replaced by a generic lambda (the macro
// likely broke the harness build):
//  * Split accumulators: acc_e (bias + Wih@e) and acc_h (Whh@h) -> 8
//    independent 4-deep MFMA chains instead of 4x 8-deep.
//  * Gate weights pre-scaled at load: i,f,o rows by -log2(e), g rows by
//    -2*log2(e)  -> sigm = rcp(1+exp2(acc)), tanh_g = 2*rcp(1+exp2(acc))-1.
//  * Time loop unrolled x2 (compile-time ping/pong phase).
// ---------------------------------------------------------------------------

#define B_TOT 4096
#define T_LEN 1024
#define D_INP 2
#define EMD   128
#define CELL  128
#define D_OUT 5

#define ROWS  16               // batch rows per block (MFMA N)
#define WAVES 8
#define BLOCK (WAVES * 64)
#define LDH   136              // padded LDS row stride in shorts

typedef short s8v  __attribute__((ext_vector_type(8)));   // 8 x bf16 MFMA frag
typedef float f32x4 __attribute__((ext_vector_type(4)));

#define BAR() asm volatile("s_waitcnt lgkmcnt(0)\n\ts_barrier" ::: "memory")

#if __has_builtin(__builtin_amdgcn_exp2f)
#define EXP2F(x) __builtin_amdgcn_exp2f(x)
#else
#define EXP2F(x) exp2f(x)
#endif
#if __has_builtin(__builtin_amdgcn_rcpf)
#define RCPF(x) __builtin_amdgcn_rcpf(x)
#else
#define RCPF(x) (1.0f / (x))
#endif

__device__ __forceinline__ short f2bf(float f) {   // RNE (init-time only)
    unsigned int u = __builtin_bit_cast(unsigned int, f);
    u += 0x7fffu + ((u >> 16) & 1u);
    return (short)(u >> 16);
}
// pack two fp32 -> two bf16 in one dword, round-nearest (ties away)
__device__ __forceinline__ unsigned int pk_bf16(float a, float b) {
    unsigned int ua = __builtin_bit_cast(unsigned int, a);
    unsigned int ub = __builtin_bit_cast(unsigned int, b);
    return ((ua + 0x8000u) >> 16) | ((ub + 0x8000u) & 0xffff0000u);
}
__device__ __forceinline__ float tanh_fast(float x) {
    return 2.0f * RCPF(1.0f + EXP2F(-2.88539008f * x)) - 1.0f;
}
__device__ __forceinline__ s8v load8_scaled(const float* p, float s) {
    float4 a = *(const float4*)p;
    float4 b = *(const float4*)(p + 4);
    s8v r;
    r[0] = f2bf(a.x * s); r[1] = f2bf(a.y * s); r[2] = f2bf(a.z * s); r[3] = f2bf(a.w * s);
    r[4] = f2bf(b.x * s); r[5] = f2bf(b.y * s); r[6] = f2bf(b.z * s); r[7] = f2bf(b.w * s);
    return r;
}

__global__ __launch_bounds__(BLOCK, 1)
void lstm_persistent(const float* __restrict__ x,     // [B,T,2]
                     const float* __restrict__ We,    // [128,2]
                     const float* __restrict__ be,    // [128]
                     const float* __restrict__ Wih,   // [512,128]
                     const float* __restrict__ Whh,   // [512,128]
                     const float* __restrict__ bih,   // [512]
                     const float* __restrict__ bhh,   // [512]
                     const float* __restrict__ Wo,    // [5,128]
                     const float* __restrict__ bo,    // [5]
                     float* __restrict__ out)         // y[B,T,5] | h[B,128] | c[B,128]
{
    __shared__ short h_lds[2][ROWS][LDH];   // [row][channel], bf16
    __shared__ short e_lds[2][ROWS][LDH];

    const int tid  = threadIdx.x;
    const int lane = tid & 63;
    const int w    = tid >> 6;         // wave 0..7
    const int n16  = lane & 15;        // B-operand index: batch row
    const int q    = lane >> 4;        // quad 0..3
    const int q8   = q * 8;
    const int b0   = blockIdx.x * ROWS;
    const int ch0  = w * 16 + q * 4;   // first of this lane's 4 channels

    float* out_y = out;
    float* out_h = out + (size_t)B_TOT * T_LEN * D_OUT;
    float* out_c = out_h + (size_t)B_TOT * CELL;

    // gate pre-scales: sigm gates -log2(e), tanh gate -2*log2(e)
    const float GSC[4] = {-1.44269504f, -1.44269504f, -2.88539008f, -1.44269504f};

    // ---- persistent weight fragments, A-operand layout A[m][k]:
    //      m = lane&15 -> channel (w*16+n16), k = q*8+j ----
    s8v wih_f[4][4], whh_f[4][4];      // [gate i/f/g/o][ktile]
    #pragma unroll
    for (int g = 0; g < 4; ++g) {
        const int row = g * CELL + w * 16 + n16;
        #pragma unroll
        for (int kt = 0; kt < 4; ++kt) {
            wih_f[g][kt] = load8_scaled(Wih + row * EMD  + kt * 32 + q8, GSC[g]);
            whh_f[g][kt] = load8_scaled(Whh + row * CELL + kt * 32 + q8, GSC[g]);
        }
    }
    // per-lane pre-scaled biases for its 4 channels (C/D row q*4+r -> ch0+r)
    float4 bias4[4];
    #pragma unroll
    for (int g = 0; g < 4; ++g) {
        float4 bi = *(const float4*)(bih + g * CELL + ch0);
        float4 bh = *(const float4*)(bhh + g * CELL + ch0);
        bias4[g] = make_float4((bi.x + bh.x) * GSC[g], (bi.y + bh.y) * GSC[g],
                               (bi.z + bh.z) * GSC[g], (bi.w + bh.w) * GSC[g]);
    }

    // ---- wave 0: output projection (unscaled). m=lane&15 -> out-channel ----
    s8v wo_f[4];
    float bo_r[4];
    {
        s8v z = {0, 0, 0, 0, 0, 0, 0, 0};
        #pragma unroll
        for (int kt = 0; kt < 4; ++kt) wo_f[kt] = z;
        if (w == 0 && n16 < D_OUT) {
            #pragma unroll
            for (int kt = 0; kt < 4; ++kt)
                wo_f[kt] = load8_scaled(Wo + n16 * CELL + kt * 32 + q8, 1.0f);
        }
        #pragma unroll
        for (int r = 0; r < 4; ++r) {
            const int oc = q * 4 + r;
            bo_r[r] = (w == 0 && oc < D_OUT) ? bo[oc] : 0.0f;
        }
    }

    // ---- embedding constants: thread handles row er, e-cols jj0..jj0+3 ----
    const int er  = tid >> 5;           // 0..15
    const int jj0 = (tid & 31) * 4;     // 0..124
    float weA[4], weB[4], bev[4];
    #pragma unroll
    for (int jl = 0; jl < 4; ++jl) {
        weA[jl] = We[(jj0 + jl) * 2 + 0];
        weB[jl] = We[(jj0 + jl) * 2 + 1];
        bev[jl] = be[jj0 + jl];
    }
    const float* xrow = x + (size_t)(b0 + er) * T_LEN * D_INP;

    // ---- prologue: h_0 = 0, e_0 into buffer 0 ----
    {
        unsigned int* hz = (unsigned int*)&h_lds[0][0][0];
        for (int i = tid; i < ROWS * LDH / 2; i += BLOCK) hz[i] = 0u;

        float2 xd = *(const float2*)(xrow);
        float e0 = fmaxf(xd.x * weA[0] + xd.y * weB[0] + bev[0], 0.0f);
        float e1 = fmaxf(xd.x * weA[1] + xd.y * weB[1] + bev[1], 0.0f);
        float e2 = fmaxf(xd.x * weA[2] + xd.y * weB[2] + bev[2], 0.0f);
        float e3 = fmaxf(xd.x * weA[3] + xd.y * weB[3] + bev[3], 0.0f);
        unsigned int* ep = (unsigned int*)&e_lds[0][er][jj0];
        ep[0] = pk_bf16(e0, e1); ep[1] = pk_bf16(e2, e3);
    }

    float c_r[4] = {0.0f, 0.0f, 0.0f, 0.0f};

    // ======================= time loop, unrolled x2 =======================
    // step(u, P): consume h_lds[P]/e_lds[P], produce h_lds[1-P]/e_lds[1-P].
    auto step = [&](int u, auto Pc) {
        constexpr int P = decltype(Pc)::value;
        BAR();   // lgkm-only: h_lds[P], e_lds[P] visible; our reads drained

        const int tn = (u + 1 < T_LEN) ? (u + 1) : (T_LEN - 1);
        float2 xd = *(const float2*)(xrow + tn * D_INP);

        s8v ah[4], ae[4];
        #pragma unroll
        for (int kt = 0; kt < 4; ++kt) {
            ah[kt] = *(const s8v*)&h_lds[P][n16][kt * 32 + q8];
            ae[kt] = *(const s8v*)&e_lds[P][n16][kt * 32 + q8];
        }

        // split accumulators: 8 independent 4-deep MFMA chains
        f32x4 acc_e[4], acc_h[4];
        #pragma unroll
        for (int g = 0; g < 4; ++g) {
            f32x4 a = {bias4[g].x, bias4[g].y, bias4[g].z, bias4[g].w};
            f32x4 b = {0.0f, 0.0f, 0.0f, 0.0f};
            #pragma unroll
            for (int kt = 0; kt < 4; ++kt) {
                a = __builtin_amdgcn_mfma_f32_16x16x32_bf16(wih_f[g][kt], ae[kt], a, 0, 0, 0);
                b = __builtin_amdgcn_mfma_f32_16x16x32_bf16(whh_f[g][kt], ah[kt], b, 0, 0, 0);
            }
            acc_e[g] = a; acc_h[g] = b;
        }

        // wave 0: y_{u-1} = Wo @ h_u^T (lagged one step)
        if (w == 0 && u > 0) {
            f32x4 ay = {bo_r[0], bo_r[1], bo_r[2], bo_r[3]};
            #pragma unroll
            for (int kt = 0; kt < 4; ++kt)
                ay = __builtin_amdgcn_mfma_f32_16x16x32_bf16(wo_f[kt], ah[kt], ay, 0, 0, 0);
            float* yp = out_y + ((size_t)(b0 + n16) * T_LEN + (u - 1)) * D_OUT;
            if (q == 0) { yp[0] = ay[0]; yp[1] = ay[1]; yp[2] = ay[2]; yp[3] = ay[3]; }
            else if (q == 1) { yp[4] = ay[0]; }
        }

        // elementwise; gates pre-scaled: sigm=rcp(1+exp2(s)), g=2*rcp-1
        float hv[4];
        #pragma unroll
        for (int r = 0; r < 4; ++r) {
            float si = acc_e[0][r] + acc_h[0][r];
            float sf = acc_e[1][r] + acc_h[1][r];
            float sg = acc_e[2][r] + acc_h[2][r];
            float so = acc_e[3][r] + acc_h[3][r];
            float iv = RCPF(1.0f + EXP2F(si));
            float fv = RCPF(1.0f + EXP2F(sf));
            float gv = 2.0f * RCPF(1.0f + EXP2F(sg)) - 1.0f;
            float ov = RCPF(1.0f + EXP2F(so));
            c_r[r] = fv * c_r[r] + iv * gv;
            hv[r] = ov * tanh_fast(c_r[r]);
        }
        {   // h_{u+1}: 4 consecutive bf16 = one 8B LDS write
            unsigned int* hp = (unsigned int*)&h_lds[1 - P][n16][ch0];
            hp[0] = pk_bf16(hv[0], hv[1]); hp[1] = pk_bf16(hv[2], hv[3]);
        }
        if (u == T_LEN - 1) {   // final h, fp32 from registers (uniform branch)
            *(float4*)(out_h + (size_t)(b0 + n16) * CELL + ch0) =
                make_float4(hv[0], hv[1], hv[2], hv[3]);
        }
        {   // e_{u+1} into the other buffer
            float e0 = fmaxf(xd.x * weA[0] + xd.y * weB[0] + bev[0], 0.0f);
            float e1 = fmaxf(xd.x * weA[1] + xd.y * weB[1] + bev[1], 0.0f);
            float e2 = fmaxf(xd.x * weA[2] + xd.y * weB[2] + bev[2], 0.0f);
            float e3 = fmaxf(xd.x * weA[3] + xd.y * weB[3] + bev[3], 0.0f);
            unsigned int* ep = (unsigned int*)&e_lds[1 - P][er][jj0];
            ep[0] = pk_bf16(e0, e1); ep[1] = pk_bf16(e2, e3);
        }
    };

    #pragma unroll 1
    for (int u = 0; u < T_LEN; u += 2) {
        step(u,     std::integral_constant<int, 0>{});
        step(u + 1, std::integral_constant<int, 1>{});
    }

    // ======================= epilogue =======================
    BAR();   // h_T lives in h_lds[0] (iter 1023 wrote buffer 0)

    if (w == 0) {   // y_{T-1} = Wo @ h_T^T
        s8v ah[4];
        #pragma unroll
        for (int kt = 0; kt < 4; ++kt)
            ah[kt] = *(const s8v*)&h_lds[0][n16][kt * 32 + q8];
        f32x4 ay = {bo_r[0], bo_r[1], bo_r[2], bo_r[3]};
        #pragma unroll
        for (int kt = 0; kt < 4; ++kt)
            ay = __builtin_amdgcn_mfma_f32_16x16x32_bf16(wo_f[kt], ah[kt], ay, 0, 0, 0);
        float* yp = out_y + ((size_t)(b0 + n16) * T_LEN + (T_LEN - 1)) * D_OUT;
        if (q == 0) {
            yp[0] = ay[0]; yp[1] = ay[1]; yp[2] = ay[2]; yp[3] = ay[3];
        } else if (q == 1) {
            yp[4] = ay[0];
        }
    }

    // final c: 4 consecutive channels -> one float4 store
    *(float4*)(out_c + (size_t)(b0 + n16) * CELL + ch0) =
        make_float4(c_r[0], c_r[1], c_r[2], c_r[3]);
}

extern "C" void kernel_launch(void* const* d_in, const int* in_sizes, int n_in,
                              void* d_out, int out_size, void* d_ws, size_t ws_size,
                              hipStream_t stream) {
    const float* x   = (const float*)d_in[0];
    const float* We  = (const float*)d_in[1];
    const float* be  = (const float*)d_in[2];
    const float* Wih = (const float*)d_in[3];
    const float* Whh = (const float*)d_in[4];
    const float* bih = (const float*)d_in[5];
    const float* bhh = (const float*)d_in[6];
    const float* Wo  = (const float*)d_in[7];
    const float* bo  = (const float*)d_in[8];
    float* out = (float*)d_out;

    dim3 grid(B_TOT / ROWS);   // 256 blocks, one per CU
    dim3 block(BLOCK);         // 512 threads = 8 waves
    hipLaunchKernelGGL(lstm_persistent, grid, block, 0, stream,
                       x, We, be, Wih, Whh, bih, bhh, Wo, bo, out);
}

// Round 6
// 1264.721 us; speedup vs baseline: 1.1057x; 1.0441x over previous
//
#include <hip/hip_runtime.h>
#include <hip/hip_bf16.h>
#include <type_traits>

// ---------------------------------------------------------------------------
// VanillaLSTM forward, persistent-RNN style. FP32 global I/O, bf16 MFMA core.
// B=4096 seqs / 256 blocks -> 16 rows per block, one block per CU.
// 512 threads = 8 waves; wave w owns cell-channel slice [w*16, w*16+16).
// Weights-stationary in VGPRs (pins the CU at 8 waves -- structural).
//
// Round 6 changes vs round 5:
//  * Merged gate accumulators (one 8-deep MFMA chain per gate, bias-init):
//    removes 16 v_add/lane/step; 8 chains/wave x 2 waves keeps pipe fed.
//  * y de-straggler: y-MFMAs ISSUED right after ah loads (latency hidden
//    under the 32 gate MFMAs), y STORED at end of step -- wave 0 no longer
//    the per-step barrier straggler.
//  * v_perm_b32-based bf16 pair packing (3 ops vs 5).
//  * x prefetch index via & (T-1) instead of select.
// ---------------------------------------------------------------------------

#define B_TOT 4096
#define T_LEN 1024
#define D_INP 2
#define EMD   128
#define CELL  128
#define D_OUT 5

#define ROWS  16               // batch rows per block (MFMA N)
#define WAVES 8
#define BLOCK (WAVES * 64)
#define LDH   136              // padded LDS row stride in shorts

typedef short s8v  __attribute__((ext_vector_type(8)));   // 8 x bf16 MFMA frag
typedef float f32x4 __attribute__((ext_vector_type(4)));

#define BAR() asm volatile("s_waitcnt lgkmcnt(0)\n\ts_barrier" ::: "memory")

#if __has_builtin(__builtin_amdgcn_exp2f)
#define EXP2F(x) __builtin_amdgcn_exp2f(x)
#else
#define EXP2F(x) exp2f(x)
#endif
#if __has_builtin(__builtin_amdgcn_rcpf)
#define RCPF(x) __builtin_amdgcn_rcpf(x)
#else
#define RCPF(x) (1.0f / (x))
#endif

__device__ __forceinline__ short f2bf(float f) {   // RNE (init-time only)
    unsigned int u = __builtin_bit_cast(unsigned int, f);
    u += 0x7fffu + ((u >> 16) & 1u);
    return (short)(u >> 16);
}
// pack two fp32 -> two bf16 in one dword (low16 = a), round-nearest ties-away:
// add 0x8000 then v_perm_b32 grabs the two high halves in one instruction.
__device__ __forceinline__ unsigned int pk2(float a, float b) {
    unsigned int ua = __builtin_bit_cast(unsigned int, a) + 0x8000u;
    unsigned int ub = __builtin_bit_cast(unsigned int, b) + 0x8000u;
    return __builtin_amdgcn_perm(ub, ua, 0x07060302);  // {ub.hi16, ua.hi16}
}
__device__ __forceinline__ float tanh_fast(float x) {
    return 2.0f * RCPF(1.0f + EXP2F(-2.88539008f * x)) - 1.0f;
}
__device__ __forceinline__ s8v load8_scaled(const float* p, float s) {
    float4 a = *(const float4*)p;
    float4 b = *(const float4*)(p + 4);
    s8v r;
    r[0] = f2bf(a.x * s); r[1] = f2bf(a.y * s); r[2] = f2bf(a.z * s); r[3] = f2bf(a.w * s);
    r[4] = f2bf(b.x * s); r[5] = f2bf(b.y * s); r[6] = f2bf(b.z * s); r[7] = f2bf(b.w * s);
    return r;
}

__global__ __launch_bounds__(BLOCK, 1)
void lstm_persistent(const float* __restrict__ x,     // [B,T,2]
                     const float* __restrict__ We,    // [128,2]
                     const float* __restrict__ be,    // [128]
                     const float* __restrict__ Wih,   // [512,128]
                     const float* __restrict__ Whh,   // [512,128]
                     const float* __restrict__ bih,   // [512]
                     const float* __restrict__ bhh,   // [512]
                     const float* __restrict__ Wo,    // [5,128]
                     const float* __restrict__ bo,    // [5]
                     float* __restrict__ out)         // y[B,T,5] | h[B,128] | c[B,128]
{
    __shared__ short h_lds[2][ROWS][LDH];   // [row][channel], bf16
    __shared__ short e_lds[2][ROWS][LDH];

    const int tid  = threadIdx.x;
    const int lane = tid & 63;
    const int w    = tid >> 6;         // wave 0..7
    const int n16  = lane & 15;        // B-operand index: batch row
    const int q    = lane >> 4;        // quad 0..3
    const int q8   = q * 8;
    const int b0   = blockIdx.x * ROWS;
    const int ch0  = w * 16 + q * 4;   // first of this lane's 4 channels

    float* out_y = out;
    float* out_h = out + (size_t)B_TOT * T_LEN * D_OUT;
    float* out_c = out_h + (size_t)B_TOT * CELL;

    // gate pre-scales: sigm gates -log2(e), tanh gate -2*log2(e)
    const float GSC[4] = {-1.44269504f, -1.44269504f, -2.88539008f, -1.44269504f};

    // ---- persistent weight fragments, A-operand layout A[m][k]:
    //      m = lane&15 -> channel (w*16+n16), k = q*8+j ----
    s8v wih_f[4][4], whh_f[4][4];      // [gate i/f/g/o][ktile]
    #pragma unroll
    for (int g = 0; g < 4; ++g) {
        const int row = g * CELL + w * 16 + n16;
        #pragma unroll
        for (int kt = 0; kt < 4; ++kt) {
            wih_f[g][kt] = load8_scaled(Wih + row * EMD  + kt * 32 + q8, GSC[g]);
            whh_f[g][kt] = load8_scaled(Whh + row * CELL + kt * 32 + q8, GSC[g]);
        }
    }
    // per-lane pre-scaled biases for its 4 channels (C/D row q*4+r -> ch0+r)
    float4 bias4[4];
    #pragma unroll
    for (int g = 0; g < 4; ++g) {
        float4 bi = *(const float4*)(bih + g * CELL + ch0);
        float4 bh = *(const float4*)(bhh + g * CELL + ch0);
        bias4[g] = make_float4((bi.x + bh.x) * GSC[g], (bi.y + bh.y) * GSC[g],
                               (bi.z + bh.z) * GSC[g], (bi.w + bh.w) * GSC[g]);
    }

    // ---- wave 0: output projection (unscaled). m=lane&15 -> out-channel ----
    s8v wo_f[4];
    float bo_r[4];
    {
        s8v z = {0, 0, 0, 0, 0, 0, 0, 0};
        #pragma unroll
        for (int kt = 0; kt < 4; ++kt) wo_f[kt] = z;
        if (w == 0 && n16 < D_OUT) {
            #pragma unroll
            for (int kt = 0; kt < 4; ++kt)
                wo_f[kt] = load8_scaled(Wo + n16 * CELL + kt * 32 + q8, 1.0f);
        }
        #pragma unroll
        for (int r = 0; r < 4; ++r) {
            const int oc = q * 4 + r;
            bo_r[r] = (w == 0 && oc < D_OUT) ? bo[oc] : 0.0f;
        }
    }

    // ---- embedding constants: thread handles row er, e-cols jj0..jj0+3 ----
    const int er  = tid >> 5;           // 0..15
    const int jj0 = (tid & 31) * 4;     // 0..124
    float weA[4], weB[4], bev[4];
    #pragma unroll
    for (int jl = 0; jl < 4; ++jl) {
        weA[jl] = We[(jj0 + jl) * 2 + 0];
        weB[jl] = We[(jj0 + jl) * 2 + 1];
        bev[jl] = be[jj0 + jl];
    }
    const float* xrow = x + (size_t)(b0 + er) * T_LEN * D_INP;

    // ---- prologue: h_0 = 0, e_0 into buffer 0 ----
    {
        unsigned int* hz = (unsigned int*)&h_lds[0][0][0];
        for (int i = tid; i < ROWS * LDH / 2; i += BLOCK) hz[i] = 0u;

        float2 xd = *(const float2*)(xrow);
        float e0 = fmaxf(xd.x * weA[0] + xd.y * weB[0] + bev[0], 0.0f);
        float e1 = fmaxf(xd.x * weA[1] + xd.y * weB[1] + bev[1], 0.0f);
        float e2 = fmaxf(xd.x * weA[2] + xd.y * weB[2] + bev[2], 0.0f);
        float e3 = fmaxf(xd.x * weA[3] + xd.y * weB[3] + bev[3], 0.0f);
        unsigned int* ep = (unsigned int*)&e_lds[0][er][jj0];
        ep[0] = pk2(e0, e1); ep[1] = pk2(e2, e3);
    }

    float c_r[4] = {0.0f, 0.0f, 0.0f, 0.0f};

    // ======================= time loop, unrolled x2 =======================
    // step(u, P): consume h_lds[P]/e_lds[P], produce h_lds[1-P]/e_lds[1-P].
    auto step = [&](int u, auto Pc) {
        constexpr int P = decltype(Pc)::value;
        BAR();   // lgkm-only: h_lds[P], e_lds[P] visible; our reads drained

        const int tn = (u + 1) & (T_LEN - 1);     // wraps to 0 at the end (dummy)
        float2 xd = *(const float2*)(xrow + tn * D_INP);

        s8v ah[4], ae[4];
        #pragma unroll
        for (int kt = 0; kt < 4; ++kt) {
            ah[kt] = *(const s8v*)&h_lds[P][n16][kt * 32 + q8];
            ae[kt] = *(const s8v*)&e_lds[P][n16][kt * 32 + q8];
        }

        // wave 0: ISSUE y_{u-1} = Wo @ h_u^T early; store at end of step.
        const bool ydo = (w == 0) && (u > 0);
        f32x4 ay;
        if (ydo) {
            ay = f32x4{bo_r[0], bo_r[1], bo_r[2], bo_r[3]};
            #pragma unroll
            for (int kt = 0; kt < 4; ++kt)
                ay = __builtin_amdgcn_mfma_f32_16x16x32_bf16(wo_f[kt], ah[kt], ay, 0, 0, 0);
        }

        // gates: one 8-deep bias-initialized chain per gate (8 chains/wave)
        f32x4 acc[4];
        #pragma unroll
        for (int g = 0; g < 4; ++g) {
            f32x4 a = {bias4[g].x, bias4[g].y, bias4[g].z, bias4[g].w};
            #pragma unroll
            for (int kt = 0; kt < 4; ++kt)
                a = __builtin_amdgcn_mfma_f32_16x16x32_bf16(wih_f[g][kt], ae[kt], a, 0, 0, 0);
            #pragma unroll
            for (int kt = 0; kt < 4; ++kt)
                a = __builtin_amdgcn_mfma_f32_16x16x32_bf16(whh_f[g][kt], ah[kt], a, 0, 0, 0);
            acc[g] = a;
        }

        // elementwise; gates pre-scaled: sigm=rcp(1+exp2(s)), g=2*rcp-1
        float hv[4];
        #pragma unroll
        for (int r = 0; r < 4; ++r) {
            float iv = RCPF(1.0f + EXP2F(acc[0][r]));
            float fv = RCPF(1.0f + EXP2F(acc[1][r]));
            float gv = 2.0f * RCPF(1.0f + EXP2F(acc[2][r])) - 1.0f;
            float ov = RCPF(1.0f + EXP2F(acc[3][r]));
            c_r[r] = fv * c_r[r] + iv * gv;
            hv[r] = ov * tanh_fast(c_r[r]);
        }
        {   // h_{u+1}: 4 consecutive bf16 = one 8B LDS write
            unsigned int* hp = (unsigned int*)&h_lds[1 - P][n16][ch0];
            hp[0] = pk2(hv[0], hv[1]); hp[1] = pk2(hv[2], hv[3]);
        }
        if (u == T_LEN - 1) {   // final h, fp32 from registers (uniform branch)
            *(float4*)(out_h + (size_t)(b0 + n16) * CELL + ch0) =
                make_float4(hv[0], hv[1], hv[2], hv[3]);
        }
        {   // e_{u+1} into the other buffer
            float e0 = fmaxf(xd.x * weA[0] + xd.y * weB[0] + bev[0], 0.0f);
            float e1 = fmaxf(xd.x * weA[1] + xd.y * weB[1] + bev[1], 0.0f);
            float e2 = fmaxf(xd.x * weA[2] + xd.y * weB[2] + bev[2], 0.0f);
            float e3 = fmaxf(xd.x * weA[3] + xd.y * weB[3] + bev[3], 0.0f);
            unsigned int* ep = (unsigned int*)&e_lds[1 - P][er][jj0];
            ep[0] = pk2(e0, e1); ep[1] = pk2(e2, e3);
        }

        // y store, long after its MFMA chain completed (streams; no vmcnt wait)
        if (ydo) {
            float* yp = out_y + ((size_t)(b0 + n16) * T_LEN + (u - 1)) * D_OUT;
            if (q == 0) { yp[0] = ay[0]; yp[1] = ay[1]; yp[2] = ay[2]; yp[3] = ay[3]; }
            else if (q == 1) { yp[4] = ay[0]; }
        }
    };

    #pragma unroll 1
    for (int u = 0; u < T_LEN; u += 2) {
        step(u,     std::integral_constant<int, 0>{});
        step(u + 1, std::integral_constant<int, 1>{});
    }

    // ======================= epilogue =======================
    BAR();   // h_T lives in h_lds[0] (iter 1023 wrote buffer 0)

    if (w == 0) {   // y_{T-1} = Wo @ h_T^T
        s8v ah[4];
        #pragma unroll
        for (int kt = 0; kt < 4; ++kt)
            ah[kt] = *(const s8v*)&h_lds[0][n16][kt * 32 + q8];
        f32x4 ay = {bo_r[0], bo_r[1], bo_r[2], bo_r[3]};
        #pragma unroll
        for (int kt = 0; kt < 4; ++kt)
            ay = __builtin_amdgcn_mfma_f32_16x16x32_bf16(wo_f[kt], ah[kt], ay, 0, 0, 0);
        float* yp = out_y + ((size_t)(b0 + n16) * T_LEN + (T_LEN - 1)) * D_OUT;
        if (q == 0) {
            yp[0] = ay[0]; yp[1] = ay[1]; yp[2] = ay[2]; yp[3] = ay[3];
        } else if (q == 1) {
            yp[4] = ay[0];
        }
    }

    // final c: 4 consecutive channels -> one float4 store
    *(float4*)(out_c + (size_t)(b0 + n16) * CELL + ch0) =
        make_float4(c_r[0], c_r[1], c_r[2], c_r[3]);
}

extern "C" void kernel_launch(void* const* d_in, const int* in_sizes, int n_in,
                              void* d_out, int out_size, void* d_ws, size_t ws_size,
                              hipStream_t stream) {
    const float* x   = (const float*)d_in[0];
    const float* We  = (const float*)d_in[1];
    const float* be  = (const float*)d_in[2];
    const float* Wih = (const float*)d_in[3];
    const float* Whh = (const float*)d_in[4];
    const float* bih = (const float*)d_in[5];
    const float* bhh = (const float*)d_in[6];
    const float* Wo  = (const float*)d_in[7];
    const float* bo  = (const float*)d_in[8];
    float* out = (float*)d_out;

    dim3 grid(B_TOT / ROWS);   // 256 blocks, one per CU
    dim3 block(BLOCK);         // 512 threads = 8 waves
    hipLaunchKernelGGL(lstm_persistent, grid, block, 0, stream,
                       x, We, be, Wih, Whh, bih, bhh, Wo, bo, out);
}

// Round 7
// 1240.635 us; speedup vs baseline: 1.1271x; 1.0194x over previous
//
#include <hip/hip_runtime.h>
#include <hip/hip_bf16.h>
#include <type_traits>

// ---------------------------------------------------------------------------
// VanillaLSTM forward, persistent-RNN style. FP32 global I/O, bf16 MFMA core.
// B=4096 seqs / 256 blocks -> 16 rows per block, one block per CU.
// 512 threads = 8 waves; wave w owns cell-channel slice [w*16, w*16+16).
// Weights-stationary in VGPRs (pins the CU at 8 waves -- structural).
//
// Round 7 change vs round 6 (attack the transcendental issue floor):
//  * Combined-reciprocal gate math. With pre-scaled gates the four exp2
//    outputs t_i,t_f,t_g,t_o give
//      c' = [c(1+t_i)(1+t_g) + (1+t_f)(1-t_g)] / [(1+t_f)(1+t_i)(1+t_g)]
//      h  = (1-t_c) / [(1+t_o)(1+t_c)],  t_c = exp2(-2log2e * c')
//    -> 5 exp2 + 2 rcp = 7 trans/element instead of 10. Saves ~380
//    cyc/SIMD/step of quarter-rate VALU issue at +6 full-rate ops.
//    Algebraically identical to the previous form (rcp is 1-ulp).
// ---------------------------------------------------------------------------

#define B_TOT 4096
#define T_LEN 1024
#define D_INP 2
#define EMD   128
#define CELL  128
#define D_OUT 5

#define ROWS  16               // batch rows per block (MFMA N)
#define WAVES 8
#define BLOCK (WAVES * 64)
#define LDH   136              // padded LDS row stride in shorts

typedef short s8v  __attribute__((ext_vector_type(8)));   // 8 x bf16 MFMA frag
typedef float f32x4 __attribute__((ext_vector_type(4)));

#define BAR() asm volatile("s_waitcnt lgkmcnt(0)\n\ts_barrier" ::: "memory")

#if __has_builtin(__builtin_amdgcn_exp2f)
#define EXP2F(x) __builtin_amdgcn_exp2f(x)
#else
#define EXP2F(x) exp2f(x)
#endif
#if __has_builtin(__builtin_amdgcn_rcpf)
#define RCPF(x) __builtin_amdgcn_rcpf(x)
#else
#define RCPF(x) (1.0f / (x))
#endif

__device__ __forceinline__ short f2bf(float f) {   // RNE (init-time only)
    unsigned int u = __builtin_bit_cast(unsigned int, f);
    u += 0x7fffu + ((u >> 16) & 1u);
    return (short)(u >> 16);
}
// pack two fp32 -> two bf16 in one dword (low16 = a), round-nearest ties-away
__device__ __forceinline__ unsigned int pk2(float a, float b) {
    unsigned int ua = __builtin_bit_cast(unsigned int, a) + 0x8000u;
    unsigned int ub = __builtin_bit_cast(unsigned int, b) + 0x8000u;
    return __builtin_amdgcn_perm(ub, ua, 0x07060302);  // {ub.hi16, ua.hi16}
}
__device__ __forceinline__ s8v load8_scaled(const float* p, float s) {
    float4 a = *(const float4*)p;
    float4 b = *(const float4*)(p + 4);
    s8v r;
    r[0] = f2bf(a.x * s); r[1] = f2bf(a.y * s); r[2] = f2bf(a.z * s); r[3] = f2bf(a.w * s);
    r[4] = f2bf(b.x * s); r[5] = f2bf(b.y * s); r[6] = f2bf(b.z * s); r[7] = f2bf(b.w * s);
    return r;
}

__global__ __launch_bounds__(BLOCK, 1)
void lstm_persistent(const float* __restrict__ x,     // [B,T,2]
                     const float* __restrict__ We,    // [128,2]
                     const float* __restrict__ be,    // [128]
                     const float* __restrict__ Wih,   // [512,128]
                     const float* __restrict__ Whh,   // [512,128]
                     const float* __restrict__ bih,   // [512]
                     const float* __restrict__ bhh,   // [512]
                     const float* __restrict__ Wo,    // [5,128]
                     const float* __restrict__ bo,    // [5]
                     float* __restrict__ out)         // y[B,T,5] | h[B,128] | c[B,128]
{
    __shared__ short h_lds[2][ROWS][LDH];   // [row][channel], bf16
    __shared__ short e_lds[2][ROWS][LDH];

    const int tid  = threadIdx.x;
    const int lane = tid & 63;
    const int w    = tid >> 6;         // wave 0..7
    const int n16  = lane & 15;        // B-operand index: batch row
    const int q    = lane >> 4;        // quad 0..3
    const int q8   = q * 8;
    const int b0   = blockIdx.x * ROWS;
    const int ch0  = w * 16 + q * 4;   // first of this lane's 4 channels

    float* out_y = out;
    float* out_h = out + (size_t)B_TOT * T_LEN * D_OUT;
    float* out_c = out_h + (size_t)B_TOT * CELL;

    // gate pre-scales: sigm gates -log2(e), tanh gate -2*log2(e)
    const float GSC[4] = {-1.44269504f, -1.44269504f, -2.88539008f, -1.44269504f};

    // ---- persistent weight fragments, A-operand layout A[m][k]:
    //      m = lane&15 -> channel (w*16+n16), k = q*8+j ----
    s8v wih_f[4][4], whh_f[4][4];      // [gate i/f/g/o][ktile]
    #pragma unroll
    for (int g = 0; g < 4; ++g) {
        const int row = g * CELL + w * 16 + n16;
        #pragma unroll
        for (int kt = 0; kt < 4; ++kt) {
            wih_f[g][kt] = load8_scaled(Wih + row * EMD  + kt * 32 + q8, GSC[g]);
            whh_f[g][kt] = load8_scaled(Whh + row * CELL + kt * 32 + q8, GSC[g]);
        }
    }
    // per-lane pre-scaled biases for its 4 channels (C/D row q*4+r -> ch0+r)
    float4 bias4[4];
    #pragma unroll
    for (int g = 0; g < 4; ++g) {
        float4 bi = *(const float4*)(bih + g * CELL + ch0);
        float4 bh = *(const float4*)(bhh + g * CELL + ch0);
        bias4[g] = make_float4((bi.x + bh.x) * GSC[g], (bi.y + bh.y) * GSC[g],
                               (bi.z + bh.z) * GSC[g], (bi.w + bh.w) * GSC[g]);
    }

    // ---- wave 0: output projection (unscaled). m=lane&15 -> out-channel ----
    s8v wo_f[4];
    float bo_r[4];
    {
        s8v z = {0, 0, 0, 0, 0, 0, 0, 0};
        #pragma unroll
        for (int kt = 0; kt < 4; ++kt) wo_f[kt] = z;
        if (w == 0 && n16 < D_OUT) {
            #pragma unroll
            for (int kt = 0; kt < 4; ++kt)
                wo_f[kt] = load8_scaled(Wo + n16 * CELL + kt * 32 + q8, 1.0f);
        }
        #pragma unroll
        for (int r = 0; r < 4; ++r) {
            const int oc = q * 4 + r;
            bo_r[r] = (w == 0 && oc < D_OUT) ? bo[oc] : 0.0f;
        }
    }

    // ---- embedding constants: thread handles row er, e-cols jj0..jj0+3 ----
    const int er  = tid >> 5;           // 0..15
    const int jj0 = (tid & 31) * 4;     // 0..124
    float weA[4], weB[4], bev[4];
    #pragma unroll
    for (int jl = 0; jl < 4; ++jl) {
        weA[jl] = We[(jj0 + jl) * 2 + 0];
        weB[jl] = We[(jj0 + jl) * 2 + 1];
        bev[jl] = be[jj0 + jl];
    }
    const float* xrow = x + (size_t)(b0 + er) * T_LEN * D_INP;

    // ---- prologue: h_0 = 0, e_0 into buffer 0 ----
    {
        unsigned int* hz = (unsigned int*)&h_lds[0][0][0];
        for (int i = tid; i < ROWS * LDH / 2; i += BLOCK) hz[i] = 0u;

        float2 xd = *(const float2*)(xrow);
        float e0 = fmaxf(xd.x * weA[0] + xd.y * weB[0] + bev[0], 0.0f);
        float e1 = fmaxf(xd.x * weA[1] + xd.y * weB[1] + bev[1], 0.0f);
        float e2 = fmaxf(xd.x * weA[2] + xd.y * weB[2] + bev[2], 0.0f);
        float e3 = fmaxf(xd.x * weA[3] + xd.y * weB[3] + bev[3], 0.0f);
        unsigned int* ep = (unsigned int*)&e_lds[0][er][jj0];
        ep[0] = pk2(e0, e1); ep[1] = pk2(e2, e3);
    }

    float c_r[4] = {0.0f, 0.0f, 0.0f, 0.0f};

    // ======================= time loop, unrolled x2 =======================
    // step(u, P): consume h_lds[P]/e_lds[P], produce h_lds[1-P]/e_lds[1-P].
    auto step = [&](int u, auto Pc) {
        constexpr int P = decltype(Pc)::value;
        BAR();   // lgkm-only: h_lds[P], e_lds[P] visible; our reads drained

        const int tn = (u + 1) & (T_LEN - 1);     // wraps to 0 at the end (dummy)
        float2 xd = *(const float2*)(xrow + tn * D_INP);

        s8v ah[4], ae[4];
        #pragma unroll
        for (int kt = 0; kt < 4; ++kt) {
            ah[kt] = *(const s8v*)&h_lds[P][n16][kt * 32 + q8];
            ae[kt] = *(const s8v*)&e_lds[P][n16][kt * 32 + q8];
        }

        // wave 0: ISSUE y_{u-1} = Wo @ h_u^T early; store at end of step.
        const bool ydo = (w == 0) && (u > 0);
        f32x4 ay;
        if (ydo) {
            ay = f32x4{bo_r[0], bo_r[1], bo_r[2], bo_r[3]};
            #pragma unroll
            for (int kt = 0; kt < 4; ++kt)
                ay = __builtin_amdgcn_mfma_f32_16x16x32_bf16(wo_f[kt], ah[kt], ay, 0, 0, 0);
        }

        // gates: one 8-deep bias-initialized chain per gate (8 chains/wave)
        f32x4 acc[4];
        #pragma unroll
        for (int g = 0; g < 4; ++g) {
            f32x4 a = {bias4[g].x, bias4[g].y, bias4[g].z, bias4[g].w};
            #pragma unroll
            for (int kt = 0; kt < 4; ++kt)
                a = __builtin_amdgcn_mfma_f32_16x16x32_bf16(wih_f[g][kt], ae[kt], a, 0, 0, 0);
            #pragma unroll
            for (int kt = 0; kt < 4; ++kt)
                a = __builtin_amdgcn_mfma_f32_16x16x32_bf16(whh_f[g][kt], ah[kt], a, 0, 0, 0);
            acc[g] = a;
        }

        // elementwise, combined-reciprocal form (7 trans/element):
        //   t_* = exp2 of pre-scaled gates; sigm(a)=1/(1+t), tanh=(1-t)/(1+t)
        //   c' = [c(1+ti)(1+tg) + (1+tf)(1-tg)] / [(1+tf)(1+ti)(1+tg)]
        //   h  = (1-tc) / [(1+to)(1+tc)]
        float hv[4];
        #pragma unroll
        for (int r = 0; r < 4; ++r) {
            float ti = EXP2F(acc[0][r]);
            float tf = EXP2F(acc[1][r]);
            float tg = EXP2F(acc[2][r]);
            float to = EXP2F(acc[3][r]);
            float pig = (1.0f + ti) * (1.0f + tg);
            float pf  = 1.0f + tf;
            float num = c_r[r] * pig + pf * (1.0f - tg);
            float rd  = RCPF(pf * pig);
            float cn  = num * rd;
            c_r[r] = cn;
            float tc = EXP2F(-2.88539008f * cn);
            float rh = RCPF((1.0f + to) * (1.0f + tc));
            hv[r] = (1.0f - tc) * rh;
        }
        {   // h_{u+1}: 4 consecutive bf16 = one 8B LDS write
            unsigned int* hp = (unsigned int*)&h_lds[1 - P][n16][ch0];
            hp[0] = pk2(hv[0], hv[1]); hp[1] = pk2(hv[2], hv[3]);
        }
        if (u == T_LEN - 1) {   // final h, fp32 from registers (uniform branch)
            *(float4*)(out_h + (size_t)(b0 + n16) * CELL + ch0) =
                make_float4(hv[0], hv[1], hv[2], hv[3]);
        }
        {   // e_{u+1} into the other buffer
            float e0 = fmaxf(xd.x * weA[0] + xd.y * weB[0] + bev[0], 0.0f);
            float e1 = fmaxf(xd.x * weA[1] + xd.y * weB[1] + bev[1], 0.0f);
            float e2 = fmaxf(xd.x * weA[2] + xd.y * weB[2] + bev[2], 0.0f);
            float e3 = fmaxf(xd.x * weA[3] + xd.y * weB[3] + bev[3], 0.0f);
            unsigned int* ep = (unsigned int*)&e_lds[1 - P][er][jj0];
            ep[0] = pk2(e0, e1); ep[1] = pk2(e2, e3);
        }

        // y store, long after its MFMA chain completed (streams; no vmcnt wait)
        if (ydo) {
            float* yp = out_y + ((size_t)(b0 + n16) * T_LEN + (u - 1)) * D_OUT;
            if (q == 0) { yp[0] = ay[0]; yp[1] = ay[1]; yp[2] = ay[2]; yp[3] = ay[3]; }
            else if (q == 1) { yp[4] = ay[0]; }
        }
    };

    #pragma unroll 1
    for (int u = 0; u < T_LEN; u += 2) {
        step(u,     std::integral_constant<int, 0>{});
        step(u + 1, std::integral_constant<int, 1>{});
    }

    // ======================= epilogue =======================
    BAR();   // h_T lives in h_lds[0] (iter 1023 wrote buffer 0)

    if (w == 0) {   // y_{T-1} = Wo @ h_T^T
        s8v ah[4];
        #pragma unroll
        for (int kt = 0; kt < 4; ++kt)
            ah[kt] = *(const s8v*)&h_lds[0][n16][kt * 32 + q8];
        f32x4 ay = {bo_r[0], bo_r[1], bo_r[2], bo_r[3]};
        #pragma unroll
        for (int kt = 0; kt < 4; ++kt)
            ay = __builtin_amdgcn_mfma_f32_16x16x32_bf16(wo_f[kt], ah[kt], ay, 0, 0, 0);
        float* yp = out_y + ((size_t)(b0 + n16) * T_LEN + (T_LEN - 1)) * D_OUT;
        if (q == 0) {
            yp[0] = ay[0]; yp[1] = ay[1]; yp[2] = ay[2]; yp[3] = ay[3];
        } else if (q == 1) {
            yp[4] = ay[0];
        }
    }

    // final c: 4 consecutive channels -> one float4 store
    *(float4*)(out_c + (size_t)(b0 + n16) * CELL + ch0) =
        make_float4(c_r[0], c_r[1], c_r[2], c_r[3]);
}

extern "C" void kernel_launch(void* const* d_in, const int* in_sizes, int n_in,
                              void* d_out, int out_size, void* d_ws, size_t ws_size,
                              hipStream_t stream) {
    const float* x   = (const float*)d_in[0];
    const float* We  = (const float*)d_in[1];
    const float* be  = (const float*)d_in[2];
    const float* Wih = (const float*)d_in[3];
    const float* Whh = (const float*)d_in[4];
    const float* bih = (const float*)d_in[5];
    const float* bhh = (const float*)d_in[6];
    const float* Wo  = (const float*)d_in[7];
    const float* bo  = (const float*)d_in[8];
    float* out = (float*)d_out;

    dim3 grid(B_TOT / ROWS);   // 256 blocks, one per CU
    dim3 block(BLOCK);         // 512 threads = 8 waves
    hipLaunchKernelGGL(lstm_persistent, grid, block, 0, stream,
                       x, We, be, Wih, Whh, bih, bhh, Wo, bo, out);
}